// Round 10
// baseline (241.340 us; speedup 1.0000x reference)
//
#include <hip/hip_runtime.h>
#include <hip/hip_bf16.h>
#include <math.h>

constexpr int BROWS = 4096;   // batch (M)
constexpr int DDIM  = 2048;   // input features (K)
constexpr int NCOMP = 4;
constexpr int DCOMP = 1024;
constexpr int NOUT  = NCOMP * DCOMP;  // 4096 output cols

typedef __attribute__((ext_vector_type(8))) short bf16x8;
typedef __attribute__((ext_vector_type(4))) float f32x4;
typedef __attribute__((ext_vector_type(4))) short s16x4;

__device__ __forceinline__ short f2bf(float f) {
  union { float f; unsigned u; } v; v.f = f;
  unsigned r = v.u + 0x7FFFu + ((v.u >> 16) & 1u);  // round-to-nearest-even
  return (short)(r >> 16);
}

#define GLOAD_LDS16(gptr, lptr) __builtin_amdgcn_global_load_lds( \
    (const __attribute__((address_space(1))) void*)(gptr),        \
    (__attribute__((address_space(3))) void*)(lptr), 16, 0, 0)

// =======================================================================
// Prep (r5-proven, ~19.5us): blocks [0,1024) gating (1 row/wave) +
// x f32->bf16; [1024,3072) Wc transpose+convert to B^T bf16.
// =======================================================================
__global__ __launch_bounds__(256) void prep_kernel(
    const float* __restrict__ x, const float* __restrict__ noise,
    const float* __restrict__ Wg, const float* __restrict__ bg,
    const float* __restrict__ Wn, const float* __restrict__ bn,
    const float* __restrict__ Wc,
    float* __restrict__ Gout, short* __restrict__ xb, short* __restrict__ WcT) {
  __shared__ float tile[64][65];
  const int bid = blockIdx.x;
  const int tid = threadIdx.x;

  if (bid < 1024) {
    const int lane = tid & 63;
    const int row  = bid * 4 + (tid >> 6);
    const float* xr = x + (size_t)row * DDIM;
    short* xbr = xb + (size_t)row * DDIM;

    float ag[4] = {0.f, 0.f, 0.f, 0.f};
    float an[4] = {0.f, 0.f, 0.f, 0.f};
#pragma unroll
    for (int i = 0; i < 8; i++) {
      int d = i * 256 + lane * 4;
      float4 v = *reinterpret_cast<const float4*>(xr + d);
      s16x4 s; s.x = f2bf(v.x); s.y = f2bf(v.y); s.z = f2bf(v.z); s.w = f2bf(v.w);
      *reinterpret_cast<s16x4*>(xbr + d) = s;
      float xv[4] = {v.x, v.y, v.z, v.w};
#pragma unroll
      for (int j = 0; j < 4; j++) {
        float4 wg = *reinterpret_cast<const float4*>(Wg + 4 * (d + j));
        float4 wn = *reinterpret_cast<const float4*>(Wn + 4 * (d + j));
        ag[0] += xv[j] * wg.x; ag[1] += xv[j] * wg.y;
        ag[2] += xv[j] * wg.z; ag[3] += xv[j] * wg.w;
        an[0] += xv[j] * wn.x; an[1] += xv[j] * wn.y;
        an[2] += xv[j] * wn.z; an[3] += xv[j] * wn.w;
      }
    }
#pragma unroll
    for (int off = 32; off > 0; off >>= 1) {
#pragma unroll
      for (int c = 0; c < 4; c++) {
        ag[c] += __shfl_xor(ag[c], off);
        an[c] += __shfl_xor(an[c], off);
      }
    }
    if (lane == 0) {
      float H[4];
#pragma unroll
      for (int c = 0; c < 4; c++) {
        float v  = an[c] + bn[c];
        float sp = (v > 20.f) ? v : log1pf(expf(v));
        H[c] = (ag[c] + bg[c]) + noise[(size_t)row * NCOMP + c] * sp;
      }
      int k = 0; float best = H[0];
#pragma unroll
      for (int c = 1; c < 4; c++) { if (H[c] > best) { best = H[c]; k = c; } }
#pragma unroll
      for (int c = 0; c < 4; c++)
        Gout[(size_t)row * NCOMP + c] = (c <= k) ? 1.0f : 0.0f;
    }
  } else {
    const int tb  = bid - 1024;
    const int o_t = tb & 15, d_t = (tb >> 4) & 31, c = tb >> 9;
    const int d0 = d_t * 64, o0 = o_t * 64;
    const int col = tid & 63, rb = tid >> 6;

    const float* src = Wc + ((size_t)c * DDIM + d0) * DCOMP + o0;
#pragma unroll
    for (int i = 0; i < 16; i++) {
      int r = rb + i * 4;
      tile[r][col] = src[(size_t)r * DCOMP + col];
    }
    __syncthreads();
    short* dst = WcT + ((size_t)c * DCOMP + o0) * DDIM + d0;
    const int o   = tid >> 2;
    const int dsb = (tid & 3) * 16;
    bf16x8 p0, p1;
#pragma unroll
    for (int k = 0; k < 8; k++) {
      p0[k] = f2bf(tile[dsb + k][o]);
      p1[k] = f2bf(tile[dsb + 8 + k][o]);
    }
    *reinterpret_cast<bf16x8*>(dst + (size_t)o * DDIM + dsb)     = p0;
    *reinterpret_cast<bf16x8*>(dst + (size_t)o * DDIM + dsb + 8) = p1;
  }
}

// =======================================================================
// Main GEMM, round-10: READ-AHEAD pipelined 8-phase schedule.
// 256x256 tile, BK=64, 8 waves (2Mx4N), r6's stage ledger (proven):
//   p1:B1.Ah1<-t1 p2:B0.Ah0<-t2 p3:B0.Bh0<-t2 p4:B0.Bh1<-t2
//   p5:B0.Ah1<-t2 p6:B1.Ah0<-t3 p7:B1.Bh0<-t3 p8:B1.Bh1<-t3
// Register sets: aP,aQ,aR (A, 8 b128 each), bA,bB (B, 4 each). Every
// ds_read issues >= 1 full phase before its consuming MFMA:
//   reads: p1 aQ<-b0.Ah1 | p2 bB<-b0.Bh1 | p3 aR<-b1.Ah0 + bA<-b1.Bh0 |
//          p5 aQ<-b1.Ah1 | p6 bB<-b1.Bh1 | p7 aP<-b0.Ah0[t2]+bA<-b0.Bh0[t2]
//   MFMA:  p1(0,0)aP.bA p2(4,0)aQ.bA p3(4,2)aQ.bB p4(0,2)aP.bB
//          p5(0,0)aR.bA p6(4,0)aQ.bA p7(4,2)aQ.bB p8(0,2)aR.bB
// Wait structure (audited: operand-ready / stage-landed / read-before-
// overwrite, each with >=1 barrier separation):
//   counted PRE-BARRIER lgkm each phase (leaves only own reads in flight);
//   vmcnt(6)+barrier at p3-top, p4-end, p7-top, p8-end (each waits stages
//   >=4 phases old). 10 barriers/iter (vs 16), no sched_barrier, no
//   lgkm(0)-after-barrier (compiler's fine-grained dep-waits are ~free
//   since operands are a phase old).
// =======================================================================
constexpr int BM = 256, BN = 256, BK = 64;
constexpr int NT = DDIM / BK;    // 32 K-tiles
constexpr int HS = 128 * 64;     // shorts per half-tile (16 KB)

#define WAITLGKM(N) asm volatile("s_waitcnt lgkmcnt(" #N ")" ::: "memory")
#define WAITVM(N)   asm volatile("s_waitcnt vmcnt(" #N ")" ::: "memory")
#define BAR         __builtin_amdgcn_s_barrier()

template<int MB, int NB>
__device__ __forceinline__ void MF(f32x4 (&acc)[8][4], bf16x8 (&a)[4][2], bf16x8 (&b)[2][2]) {
  __builtin_amdgcn_s_setprio(1);
#pragma unroll
  for (int kh = 0; kh < 2; kh++)
#pragma unroll
    for (int ml = 0; ml < 4; ml++)
#pragma unroll
      for (int nl = 0; nl < 2; nl++)
        acc[MB + ml][NB + nl] = __builtin_amdgcn_mfma_f32_16x16x32_bf16(
            a[ml][kh], b[nl][kh], acc[MB + ml][NB + nl], 0, 0, 0);
  __builtin_amdgcn_s_setprio(0);
}

__global__ __launch_bounds__(512, 2) void gemm_kernel(
    const short* __restrict__ xb, const short* __restrict__ wt,
    const float* __restrict__ bc, const float* __restrict__ G,
    float* __restrict__ E) {
  __shared__ short Asm[2][2][HS];   // [buf][row-half][128r * 8slot * 8bf16]
  __shared__ short Bsm[2][2][HS];   // [buf][col-half][...]

  const int tid  = threadIdx.x;
  const int wave = tid >> 6, lane = tid & 63;
  const int wm = wave >> 2, wn = wave & 3;
  const int fr = lane & 15, fq = lane >> 4, l7 = lane & 7;

  // XCD swizzle: 16x16 tile grid, 8 XCDs, each owns a 4x8 chunk (col-major)
  const int xcd = blockIdx.x & 7, j = blockIdx.x >> 3;
  const int trow0 = (((xcd >> 1) << 2) + (j & 3)) * BM;
  const int tcol0 = (((xcd & 1) << 3) + (j >> 2)) * BN;

  const short* baseA[2] = { xb + (size_t)(trow0      ) * DDIM,
                            xb + (size_t)(trow0 + 128) * DDIM };
  const short* baseB[2] = { wt + (size_t)(tcol0      ) * DDIM,
                            wt + (size_t)(tcol0 + 128) * DDIM };

  // per-lane staging offsets (linear LDS dest, inverse-swizzled source)
  size_t soff[2]; int ldst[2];
#pragma unroll
  for (int l = 0; l < 2; l++) {
    int f = l * 512 + tid;
    int r = f >> 3;
    int s = (f & 7) ^ (r & 7);
    soff[l] = (size_t)r * DDIM + s * 8;
    ldst[l] = (l * 512 + wave * 64) * 8;   // wave-uniform LDS base (shorts)
  }

  auto STAGE = [&](const short* gb, int t, short* ldsh) {
#pragma unroll
    for (int l = 0; l < 2; l++)
      GLOAD_LDS16(gb + t * 64 + soff[l], ldsh + ldst[l]);
  };
  auto LDA = [&](const short* Ah, bf16x8 (&a)[4][2]) {
#pragma unroll
    for (int ml = 0; ml < 4; ml++) {
      int rh = wm * 64 + ml * 16 + fr;
#pragma unroll
      for (int kh = 0; kh < 2; kh++) {
        int sl = ((kh * 4 + fq) ^ l7) * 8;
        a[ml][kh] = *reinterpret_cast<const bf16x8*>(Ah + rh * 64 + sl);
      }
    }
  };
  auto LDB = [&](const short* Bh, bf16x8 (&b)[2][2]) {
#pragma unroll
    for (int nl = 0; nl < 2; nl++) {
      int ch = wn * 32 + nl * 16 + fr;
#pragma unroll
      for (int kh = 0; kh < 2; kh++) {
        int sl = ((kh * 4 + fq) ^ l7) * 8;
        b[nl][kh] = *reinterpret_cast<const bf16x8*>(Bh + ch * 64 + sl);
      }
    }
  };

  f32x4 acc[8][4];
#pragma unroll
  for (int m = 0; m < 8; m++)
#pragma unroll
    for (int n = 0; n < 4; n++) acc[m][n] = f32x4{0.f, 0.f, 0.f, 0.f};
  bf16x8 aP[4][2], aQ[4][2], aR[4][2], bA[2][2], bB[2][2];

  // ---- prologue: b0 <- tile0 (4 halves), b1 <- tile1 {Ah0,Bh0,Bh1};
  // vmcnt(6) leaves exactly the 3 b1 stages in flight (= steady-state
  // prev{p6,p7,p8}); pre-read aP,bA (forced by p1's lgkm(8)). ----
  STAGE(baseA[0], 0, &Asm[0][0][0]);
  STAGE(baseB[0], 0, &Bsm[0][0][0]);
  STAGE(baseA[1], 0, &Asm[0][1][0]);
  STAGE(baseB[1], 0, &Bsm[0][1][0]);
  STAGE(baseA[0], 1, &Asm[1][0][0]);
  STAGE(baseB[0], 1, &Bsm[1][0][0]);
  STAGE(baseB[1], 1, &Bsm[1][1][0]);
  WAITVM(6);
  BAR;
  LDA(&Asm[0][0][0], aP);   // b0.Ah0 -> used p1,p4
  LDB(&Bsm[0][0][0], bA);   // b0.Bh0 -> used p1,p2

  // ---- main loop (iters 0..NT/2-2) ----
  for (int i = 0; i < NT / 2 - 1; i++) {
    const int t1 = 2 * i + 1, t2 = 2 * i + 2, t3 = 2 * i + 3;

    // p1: read aQ<-b0.Ah1 (for p2,p3); MFMA(0,0)
    LDA(&Asm[0][1][0], aQ);
    STAGE(baseA[1], t1, &Asm[1][1][0]);
    WAITLGKM(8); BAR;
    MF<0, 0>(acc, aP, bA);
    // p2: read bB<-b0.Bh1 (for p3,p4); MFMA(4,0)
    LDB(&Bsm[0][1][0], bB);
    STAGE(baseA[0], t2, &Asm[0][0][0]);
    WAITLGKM(4); BAR;
    MF<4, 0>(acc, aQ, bA);
    // p3: drain point; read aR<-b1.Ah0, bA<-b1.Bh0 (for p5+); MFMA(4,2)
    WAITLGKM(0); WAITVM(6); BAR;
    LDA(&Asm[1][0][0], aR); LDB(&Bsm[1][0][0], bA);
    STAGE(baseB[0], t2, &Bsm[0][0][0]);
    MF<4, 2>(acc, aQ, bB);
    // p4: no reads; MFMA(0,2); drain point
    STAGE(baseB[1], t2, &Bsm[0][1][0]);
    BAR;
    MF<0, 2>(acc, aP, bB);
    WAITVM(6); BAR;
    // p5: read aQ<-b1.Ah1 (for p6,p7); MFMA(0,0) buf1
    LDA(&Asm[1][1][0], aQ);
    STAGE(baseA[1], t2, &Asm[0][1][0]);
    WAITLGKM(8); BAR;
    MF<0, 0>(acc, aR, bA);
    // p6: read bB<-b1.Bh1 (for p7,p8); MFMA(4,0)
    LDB(&Bsm[1][1][0], bB);
    STAGE(baseA[0], t3, &Asm[1][0][0]);
    WAITLGKM(4); BAR;
    MF<4, 0>(acc, aQ, bA);
    // p7: drain point; read aP<-b0.Ah0[t2], bA<-b0.Bh0[t2]; MFMA(4,2)
    WAITLGKM(0); WAITVM(6); BAR;
    LDA(&Asm[0][0][0], aP); LDB(&Bsm[0][0][0], bA);
    STAGE(baseB[0], t3, &Bsm[1][0][0]);
    MF<4, 2>(acc, aQ, bB);
    // p8: no reads; MFMA(0,2); drain point + read-force for next p2/p3 stages
    STAGE(baseB[1], t3, &Bsm[1][1][0]);
    BAR;
    MF<0, 2>(acc, aR, bB);
    WAITVM(6); WAITLGKM(0); BAR;
  }

  // ---- peel (tiles NT-2 buf0, NT-1 buf1): keeps p1's stage; no others.
  // vmcnt drains: p3-top (4) -> prev p6,p7; p4-end (0) -> prev p8 + p1. ----
  {
    // p1
    LDA(&Asm[0][1][0], aQ);
    STAGE(baseA[1], NT - 1, &Asm[1][1][0]);
    WAITLGKM(8); BAR;
    MF<0, 0>(acc, aP, bA);
    // p2
    LDB(&Bsm[0][1][0], bB);
    WAITLGKM(4); BAR;
    MF<4, 0>(acc, aQ, bA);
    // p3
    WAITLGKM(0); WAITVM(4); BAR;
    LDA(&Asm[1][0][0], aR); LDB(&Bsm[1][0][0], bA);
    MF<4, 2>(acc, aQ, bB);
    // p4
    BAR;
    MF<0, 2>(acc, aP, bB);
    WAITVM(0); BAR;
    // p5
    LDA(&Asm[1][1][0], aQ);
    WAITLGKM(8); BAR;
    MF<0, 0>(acc, aR, bA);
    // p6
    LDB(&Bsm[1][1][0], bB);
    WAITLGKM(4); BAR;
    MF<4, 0>(acc, aQ, bA);
    // p7
    WAITLGKM(0); BAR;
    MF<4, 2>(acc, aQ, bB);
    // p8
    BAR;
    MF<0, 2>(acc, aR, bB);
  }

  // ---- epilogue: + bias, * mask, store f32 (r9 form, unchanged) ----
  const int comp = tcol0 >> 10;
  const float* __restrict__ bcn = bc + (size_t)comp * DCOMP + (tcol0 & (DCOMP - 1));
  float bias[4];
#pragma unroll
  for (int n = 0; n < 4; n++)
    bias[n] = bcn[((n >> 1) * 128) + wn * 32 + (n & 1) * 16 + fr];
#pragma unroll
  for (int m = 0; m < 8; m++) {
    int growb = trow0 + ((m >> 2) * 128) + wm * 64 + (m & 3) * 16 + fq * 4;
#pragma unroll
    for (int j2 = 0; j2 < 4; j2++) {
      int r = growb + j2;
      float mval = G[(size_t)r * NCOMP + comp];
      float* Erow = E + (size_t)r * NOUT + tcol0;
#pragma unroll
      for (int n = 0; n < 4; n++) {
        int coll = ((n >> 1) * 128) + wn * 32 + (n & 1) * 16 + fr;
        Erow[coll] = mval * (acc[m][n][j2] + bias[n]);
      }
    }
  }
}

extern "C" void kernel_launch(void* const* d_in, const int* in_sizes, int n_in,
                              void* d_out, int out_size, void* d_ws, size_t ws_size,
                              hipStream_t stream) {
  const float* x     = (const float*)d_in[0];
  const float* noise = (const float*)d_in[1];
  const float* Wc    = (const float*)d_in[2];
  const float* bc    = (const float*)d_in[3];
  const float* Wg    = (const float*)d_in[4];
  const float* bg    = (const float*)d_in[5];
  const float* Wn    = (const float*)d_in[6];
  const float* bn    = (const float*)d_in[7];

  float* E = (float*)d_out;                          // [4096, 4096]
  float* G = (float*)d_out + (size_t)BROWS * NOUT;   // [4096, 4]

  short* xb  = (short*)d_ws;                         // 16 MB bf16
  short* WcT = xb + (size_t)BROWS * DDIM;            // 16 MB bf16

  prep_kernel<<<3072, 256, 0, stream>>>(x, noise, Wg, bg, Wn, bn, Wc, G, xb, WcT);
  gemm_kernel<<<256, 512, 0, stream>>>(xb, WcT, bc, G, E);
}

// Round 11
// 100.663 us; speedup vs baseline: 2.3975x; 2.3975x over previous
//
#include <hip/hip_runtime.h>
#include <hip/hip_bf16.h>
#include <math.h>

constexpr int BROWS = 4096;   // batch (M)
constexpr int DDIM  = 2048;   // input features (K)
constexpr int NCOMP = 4;
constexpr int DCOMP = 1024;
constexpr int NOUT  = NCOMP * DCOMP;  // 4096 output cols

typedef __attribute__((ext_vector_type(8)))  short bf16x8;
typedef __attribute__((ext_vector_type(16))) float f32x16;
typedef __attribute__((ext_vector_type(4)))  short s16x4;

__device__ __forceinline__ short f2bf(float f) {
  union { float f; unsigned u; } v; v.f = f;
  unsigned r = v.u + 0x7FFFu + ((v.u >> 16) & 1u);  // round-to-nearest-even
  return (short)(r >> 16);
}

#define GLOAD_LDS16(gptr, lptr) __builtin_amdgcn_global_load_lds( \
    (const __attribute__((address_space(1))) void*)(gptr),        \
    (__attribute__((address_space(3))) void*)(lptr), 16, 0, 0)

// =======================================================================
// Prep (r5-proven, ~19.5us): blocks [0,1024) gating (1 row/wave) +
// x f32->bf16; [1024,3072) Wc transpose+convert to B^T bf16.
// =======================================================================
__global__ __launch_bounds__(256) void prep_kernel(
    const float* __restrict__ x, const float* __restrict__ noise,
    const float* __restrict__ Wg, const float* __restrict__ bg,
    const float* __restrict__ Wn, const float* __restrict__ bn,
    const float* __restrict__ Wc,
    float* __restrict__ Gout, short* __restrict__ xb, short* __restrict__ WcT) {
  __shared__ float tile[64][65];
  const int bid = blockIdx.x;
  const int tid = threadIdx.x;

  if (bid < 1024) {
    const int lane = tid & 63;
    const int row  = bid * 4 + (tid >> 6);
    const float* xr = x + (size_t)row * DDIM;
    short* xbr = xb + (size_t)row * DDIM;

    float ag[4] = {0.f, 0.f, 0.f, 0.f};
    float an[4] = {0.f, 0.f, 0.f, 0.f};
#pragma unroll
    for (int i = 0; i < 8; i++) {
      int d = i * 256 + lane * 4;
      float4 v = *reinterpret_cast<const float4*>(xr + d);
      s16x4 s; s.x = f2bf(v.x); s.y = f2bf(v.y); s.z = f2bf(v.z); s.w = f2bf(v.w);
      *reinterpret_cast<s16x4*>(xbr + d) = s;
      float xv[4] = {v.x, v.y, v.z, v.w};
#pragma unroll
      for (int j = 0; j < 4; j++) {
        float4 wg = *reinterpret_cast<const float4*>(Wg + 4 * (d + j));
        float4 wn = *reinterpret_cast<const float4*>(Wn + 4 * (d + j));
        ag[0] += xv[j] * wg.x; ag[1] += xv[j] * wg.y;
        ag[2] += xv[j] * wg.z; ag[3] += xv[j] * wg.w;
        an[0] += xv[j] * wn.x; an[1] += xv[j] * wn.y;
        an[2] += xv[j] * wn.z; an[3] += xv[j] * wn.w;
      }
    }
#pragma unroll
    for (int off = 32; off > 0; off >>= 1) {
#pragma unroll
      for (int c = 0; c < 4; c++) {
        ag[c] += __shfl_xor(ag[c], off);
        an[c] += __shfl_xor(an[c], off);
      }
    }
    if (lane == 0) {
      float H[4];
#pragma unroll
      for (int c = 0; c < 4; c++) {
        float v  = an[c] + bn[c];
        float sp = (v > 20.f) ? v : log1pf(expf(v));
        H[c] = (ag[c] + bg[c]) + noise[(size_t)row * NCOMP + c] * sp;
      }
      int k = 0; float best = H[0];
#pragma unroll
      for (int c = 1; c < 4; c++) { if (H[c] > best) { best = H[c]; k = c; } }
#pragma unroll
      for (int c = 0; c < 4; c++)
        Gout[(size_t)row * NCOMP + c] = (c <= k) ? 1.0f : 0.0f;
    }
  } else {
    const int tb  = bid - 1024;
    const int o_t = tb & 15, d_t = (tb >> 4) & 31, c = tb >> 9;
    const int d0 = d_t * 64, o0 = o_t * 64;
    const int col = tid & 63, rb = tid >> 6;

    const float* src = Wc + ((size_t)c * DDIM + d0) * DCOMP + o0;
#pragma unroll
    for (int i = 0; i < 16; i++) {
      int r = rb + i * 4;
      tile[r][col] = src[(size_t)r * DCOMP + col];
    }
    __syncthreads();
    short* dst = WcT + ((size_t)c * DCOMP + o0) * DDIM + d0;
    const int o   = tid >> 2;
    const int dsb = (tid & 3) * 16;
    bf16x8 p0, p1;
#pragma unroll
    for (int k = 0; k < 8; k++) {
      p0[k] = f2bf(tile[dsb + k][o]);
      p1[k] = f2bf(tile[dsb + 8 + k][o]);
    }
    *reinterpret_cast<bf16x8*>(dst + (size_t)o * DDIM + dsb)     = p0;
    *reinterpret_cast<bf16x8*>(dst + (size_t)o * DDIM + dsb + 8) = p1;
  }
}

// =======================================================================
// Main GEMM, round-11: r9 chassis (proven 72.3us schedule: stage ledger,
// vmcnt(6)@p4/p8, bare lgkm(0) per phase, 128KiB dbuf LDS, XOR swizzle,
// XCD 4x8 chunks) with v_mfma_f32_32x32x16_bf16 (2495 vs 2075 TF ubench;
// half the MFMA instructions). Per phase: LDA 8 b128, LDB 4 b128 (same
// counts as r9). A-frag: row=lane&31, k=kt*16+(lane>>5)*8+j. C/D map
// (HW-verified m74/m101): col=lane&31, row=(reg&3)+8*(reg>>2)+4*(lane>>5).
// Quadrants: MH in {0,1} row-half, NB in {0,1} col-half; wave tile 128x64
// = 4 m-tiles(32) x 2 col-halves, acc = f32x16[4][2] (128 VGPR, same).
// =======================================================================
constexpr int BM = 256, BN = 256, BK = 64;
constexpr int NT = DDIM / BK;    // 32 K-tiles
constexpr int HS = 128 * 64;     // shorts per half-tile (16 KB)

template<int MH, int NB>
__device__ __forceinline__ void MF(f32x16 (&acc)[4][2], bf16x8 (&a)[2][4], bf16x8 (&b)[4]) {
#pragma unroll
  for (int kt = 0; kt < 4; kt++)
#pragma unroll
    for (int mi = 0; mi < 2; mi++)
      acc[MH * 2 + mi][NB] = __builtin_amdgcn_mfma_f32_32x32x16_bf16(
          a[mi][kt], b[kt], acc[MH * 2 + mi][NB], 0, 0, 0);
}

#define PH_SYNC_MFMA(MH, NB, BREG)                           \
  __builtin_amdgcn_s_barrier();                              \
  asm volatile("s_waitcnt lgkmcnt(0)");                      \
  __builtin_amdgcn_s_setprio(1);                             \
  MF<MH, NB>(acc, a, BREG);                                  \
  __builtin_amdgcn_s_setprio(0);

__global__ __launch_bounds__(512, 2) void gemm_kernel(
    const short* __restrict__ xb, const short* __restrict__ wt,
    const float* __restrict__ bc, const float* __restrict__ G,
    float* __restrict__ E) {
  __shared__ short Asm[2][2][HS];   // [buf][row-half][128r * 8slot * 8bf16]
  __shared__ short Bsm[2][2][HS];   // [buf][col-half][...]

  const int tid  = threadIdx.x;
  const int wave = tid >> 6, lane = tid & 63;
  const int wm = wave >> 2, wn = wave & 3;
  const int l31 = lane & 31, fq5 = lane >> 5, l7 = lane & 7;

  // XCD swizzle: 16x16 tile grid, 8 XCDs, each owns a 4x8 chunk (col-major)
  const int xcd = blockIdx.x & 7, j = blockIdx.x >> 3;
  const int trow0 = (((xcd >> 1) << 2) + (j & 3)) * BM;
  const int tcol0 = (((xcd & 1) << 3) + (j >> 2)) * BN;

  const short* baseA[2] = { xb + (size_t)(trow0      ) * DDIM,
                            xb + (size_t)(trow0 + 128) * DDIM };
  const short* baseB[2] = { wt + (size_t)(tcol0      ) * DDIM,
                            wt + (size_t)(tcol0 + 128) * DDIM };

  // per-lane staging offsets (linear LDS dest, inverse-swizzled source) —
  // byte-identical to r9 (LDS layout unchanged).
  size_t soff[2]; int ldst[2];
#pragma unroll
  for (int l = 0; l < 2; l++) {
    int f = l * 512 + tid;
    int r = f >> 3;
    int s = (f & 7) ^ (r & 7);
    soff[l] = (size_t)r * DDIM + s * 8;
    ldst[l] = (l * 512 + wave * 64) * 8;   // wave-uniform LDS base (shorts)
  }

  auto STAGE = [&](const short* gb, int t, short* ldsh) {
#pragma unroll
    for (int l = 0; l < 2; l++)
      GLOAD_LDS16(gb + t * 64 + soff[l], ldsh + ldst[l]);
  };
  // A-frag for 32x32x16: row = wm*64 + mi*32 + (lane&31); k-slot = kt*2 +
  // (lane>>5), XOR-unswizzled with row&7 (= lane&7 since bases are mult-32).
  auto LDA = [&](const short* Ah, bf16x8 (&a)[2][4]) {
#pragma unroll
    for (int mi = 0; mi < 2; mi++) {
      int rh = wm * 64 + mi * 32 + l31;
#pragma unroll
      for (int kt = 0; kt < 4; kt++) {
        int sl = ((kt * 2 + fq5) ^ l7) * 8;
        a[mi][kt] = *reinterpret_cast<const bf16x8*>(Ah + rh * 64 + sl);
      }
    }
  };
  auto LDB = [&](const short* Bh, bf16x8 (&b)[4]) {
    int ch = wn * 32 + l31;
#pragma unroll
    for (int kt = 0; kt < 4; kt++) {
      int sl = ((kt * 2 + fq5) ^ l7) * 8;
      b[kt] = *reinterpret_cast<const bf16x8*>(Bh + ch * 64 + sl);
    }
  };

  f32x16 acc[4][2];
#pragma unroll
  for (int m = 0; m < 4; m++)
#pragma unroll
    for (int n = 0; n < 2; n++)
#pragma unroll
      for (int e = 0; e < 16; e++) acc[m][n][e] = 0.f;
  bf16x8 a[2][4], bA[4], bB[4];

  // ---- prologue: tile0 (4 halves) + tile1 {Ah0,Bh0,Bh1}; vmcnt(6) keeps
  // the tile1 trio in flight; tile1.Ah1 staged at p1 of iter 0. ----
  STAGE(baseA[0], 0, &Asm[0][0][0]);
  STAGE(baseB[0], 0, &Bsm[0][0][0]);
  STAGE(baseB[1], 0, &Bsm[0][1][0]);
  STAGE(baseA[1], 0, &Asm[0][1][0]);
  STAGE(baseA[0], 1, &Asm[1][0][0]);
  STAGE(baseB[0], 1, &Bsm[1][0][0]);
  STAGE(baseB[1], 1, &Bsm[1][1][0]);
  asm volatile("s_waitcnt vmcnt(6)" ::: "memory");
  __builtin_amdgcn_s_barrier();

  // ---- main loop (iters 0..NT/2-2, branch-free; r9 ledger verbatim) ----
  for (int i = 0; i < NT / 2 - 1; i++) {
    const int t1 = 2 * i + 1, t2 = 2 * i + 2, t3 = 2 * i + 3;

    // p1: (mh0, nh0) of buf0; bA <- B0.Bh0 (held through p4)
    LDA(&Asm[0][0][0], a); LDB(&Bsm[0][0][0], bA);
    STAGE(baseA[1], t1, &Asm[1][1][0]);
    PH_SYNC_MFMA(0, 0, bA);
    __builtin_amdgcn_s_barrier();
    // p2: (mh0, nh1); bB <- B0.Bh1
    LDB(&Bsm[0][1][0], bB);
    STAGE(baseA[0], t2, &Asm[0][0][0]);
    PH_SYNC_MFMA(0, 1, bB);
    __builtin_amdgcn_s_barrier();
    // p3: (mh1, nh1)
    LDA(&Asm[0][1][0], a);
    STAGE(baseB[0], t2, &Bsm[0][0][0]);
    PH_SYNC_MFMA(1, 1, bB);
    __builtin_amdgcn_s_barrier();
    // p4: (mh1, nh0) — pure registers + counted vmcnt
    STAGE(baseB[1], t2, &Bsm[0][1][0]);
    PH_SYNC_MFMA(1, 0, bA);
    asm volatile("s_waitcnt vmcnt(6)" ::: "memory");
    __builtin_amdgcn_s_barrier();
    // p5: (mh0, nh0) of buf1
    LDA(&Asm[1][0][0], a); LDB(&Bsm[1][0][0], bA);
    STAGE(baseA[1], t2, &Asm[0][1][0]);
    PH_SYNC_MFMA(0, 0, bA);
    __builtin_amdgcn_s_barrier();
    // p6: (mh0, nh1)
    LDB(&Bsm[1][1][0], bB);
    STAGE(baseA[0], t3, &Asm[1][0][0]);
    PH_SYNC_MFMA(0, 1, bB);
    __builtin_amdgcn_s_barrier();
    // p7: (mh1, nh1)
    LDA(&Asm[1][1][0], a);
    STAGE(baseB[0], t3, &Bsm[1][0][0]);
    PH_SYNC_MFMA(1, 1, bB);
    __builtin_amdgcn_s_barrier();
    // p8: (mh1, nh0) — pure registers + counted vmcnt
    STAGE(baseB[1], t3, &Bsm[1][1][0]);
    PH_SYNC_MFMA(1, 0, bA);
    asm volatile("s_waitcnt vmcnt(6)" ::: "memory");
    __builtin_amdgcn_s_barrier();
  }

  // ---- peeled last iteration (tiles NT-2 buf0, NT-1 buf1): keeps only
  // the p1 stage (buf1.Ah1 <- NT-1); p4's vmcnt(0) drains everything. ----
  {
    // p1
    LDA(&Asm[0][0][0], a); LDB(&Bsm[0][0][0], bA);
    STAGE(baseA[1], NT - 1, &Asm[1][1][0]);
    PH_SYNC_MFMA(0, 0, bA);
    __builtin_amdgcn_s_barrier();
    // p2
    LDB(&Bsm[0][1][0], bB);
    PH_SYNC_MFMA(0, 1, bB);
    __builtin_amdgcn_s_barrier();
    // p3
    LDA(&Asm[0][1][0], a);
    PH_SYNC_MFMA(1, 1, bB);
    __builtin_amdgcn_s_barrier();
    // p4 + full drain
    PH_SYNC_MFMA(1, 0, bA);
    asm volatile("s_waitcnt vmcnt(0)" ::: "memory");
    __builtin_amdgcn_s_barrier();
    // p5
    LDA(&Asm[1][0][0], a); LDB(&Bsm[1][0][0], bA);
    PH_SYNC_MFMA(0, 0, bA);
    __builtin_amdgcn_s_barrier();
    // p6
    LDB(&Bsm[1][1][0], bB);
    PH_SYNC_MFMA(0, 1, bB);
    __builtin_amdgcn_s_barrier();
    // p7
    LDA(&Asm[1][1][0], a);
    PH_SYNC_MFMA(1, 1, bB);
    __builtin_amdgcn_s_barrier();
    // p8
    PH_SYNC_MFMA(1, 0, bA);
  }

  // ---- epilogue: + bias, * mask, store f32. 32x32 C/D map (m74/m101):
  // col = lane&31, row = (reg&3) + 8*(reg>>2) + 4*(lane>>5). ----
  const int comp = tcol0 >> 10;
  const float* __restrict__ bcn = bc + (size_t)comp * DCOMP + (tcol0 & (DCOMP - 1));
  const int rb4 = fq5 * 4;
  float bias[2];
#pragma unroll
  for (int nb = 0; nb < 2; nb++)
    bias[nb] = bcn[nb * 128 + wn * 32 + l31];
#pragma unroll
  for (int h = 0; h < 2; h++) {
#pragma unroll
    for (int mi = 0; mi < 2; mi++) {
      const int rowbase = trow0 + h * 128 + wm * 64 + mi * 32 + rb4;
#pragma unroll
      for (int jr = 0; jr < 16; jr++) {
        int r = rowbase + (jr & 3) + 8 * (jr >> 2);
        float mval = G[(size_t)r * NCOMP + comp];
        float* Erow = E + (size_t)r * NOUT + tcol0;
        Erow[wn * 32 + l31]       = mval * (acc[h * 2 + mi][0][jr] + bias[0]);
        Erow[128 + wn * 32 + l31] = mval * (acc[h * 2 + mi][1][jr] + bias[1]);
      }
    }
  }
}

extern "C" void kernel_launch(void* const* d_in, const int* in_sizes, int n_in,
                              void* d_out, int out_size, void* d_ws, size_t ws_size,
                              hipStream_t stream) {
  const float* x     = (const float*)d_in[0];
  const float* noise = (const float*)d_in[1];
  const float* Wc    = (const float*)d_in[2];
  const float* bc    = (const float*)d_in[3];
  const float* Wg    = (const float*)d_in[4];
  const float* bg    = (const float*)d_in[5];
  const float* Wn    = (const float*)d_in[6];
  const float* bn    = (const float*)d_in[7];

  float* E = (float*)d_out;                          // [4096, 4096]
  float* G = (float*)d_out + (size_t)BROWS * NOUT;   // [4096, 4]

  short* xb  = (short*)d_ws;                         // 16 MB bf16
  short* WcT = xb + (size_t)BROWS * DDIM;            // 16 MB bf16

  prep_kernel<<<3072, 256, 0, stream>>>(x, noise, Wg, bg, Wn, bn, Wc, G, xb, WcT);
  gemm_kernel<<<256, 512, 0, stream>>>(xb, WcT, bc, G, E);
}

// Round 12
// 91.723 us; speedup vs baseline: 2.6312x; 1.0975x over previous
//
#include <hip/hip_runtime.h>
#include <hip/hip_bf16.h>
#include <math.h>

constexpr int BROWS = 4096;   // batch (M)
constexpr int DDIM  = 2048;   // input features (K)
constexpr int NCOMP = 4;
constexpr int DCOMP = 1024;
constexpr int NOUT  = NCOMP * DCOMP;  // 4096 output cols

typedef __attribute__((ext_vector_type(8))) short bf16x8;
typedef __attribute__((ext_vector_type(4))) float f32x4;
typedef __attribute__((ext_vector_type(4))) short s16x4;

__device__ __forceinline__ short f2bf(float f) {
  union { float f; unsigned u; } v; v.f = f;
  unsigned r = v.u + 0x7FFFu + ((v.u >> 16) & 1u);  // round-to-nearest-even
  return (short)(r >> 16);
}

#define GLOAD_LDS16(gptr, lptr) __builtin_amdgcn_global_load_lds( \
    (const __attribute__((address_space(1))) void*)(gptr),        \
    (__attribute__((address_space(3))) void*)(lptr), 16, 0, 0)

// =======================================================================
// Prep (r5-proven, ~19.5us): blocks [0,1024) gating (1 row/wave) +
// x f32->bf16; [1024,3072) Wc transpose+convert to B^T bf16.
// =======================================================================
__global__ __launch_bounds__(256) void prep_kernel(
    const float* __restrict__ x, const float* __restrict__ noise,
    const float* __restrict__ Wg, const float* __restrict__ bg,
    const float* __restrict__ Wn, const float* __restrict__ bn,
    const float* __restrict__ Wc,
    float* __restrict__ Gout, short* __restrict__ xb, short* __restrict__ WcT) {
  __shared__ float tile[64][65];
  const int bid = blockIdx.x;
  const int tid = threadIdx.x;

  if (bid < 1024) {
    const int lane = tid & 63;
    const int row  = bid * 4 + (tid >> 6);
    const float* xr = x + (size_t)row * DDIM;
    short* xbr = xb + (size_t)row * DDIM;

    float ag[4] = {0.f, 0.f, 0.f, 0.f};
    float an[4] = {0.f, 0.f, 0.f, 0.f};
#pragma unroll
    for (int i = 0; i < 8; i++) {
      int d = i * 256 + lane * 4;
      float4 v = *reinterpret_cast<const float4*>(xr + d);
      s16x4 s; s.x = f2bf(v.x); s.y = f2bf(v.y); s.z = f2bf(v.z); s.w = f2bf(v.w);
      *reinterpret_cast<s16x4*>(xbr + d) = s;
      float xv[4] = {v.x, v.y, v.z, v.w};
#pragma unroll
      for (int j = 0; j < 4; j++) {
        float4 wg = *reinterpret_cast<const float4*>(Wg + 4 * (d + j));
        float4 wn = *reinterpret_cast<const float4*>(Wn + 4 * (d + j));
        ag[0] += xv[j] * wg.x; ag[1] += xv[j] * wg.y;
        ag[2] += xv[j] * wg.z; ag[3] += xv[j] * wg.w;
        an[0] += xv[j] * wn.x; an[1] += xv[j] * wn.y;
        an[2] += xv[j] * wn.z; an[3] += xv[j] * wn.w;
      }
    }
#pragma unroll
    for (int off = 32; off > 0; off >>= 1) {
#pragma unroll
      for (int c = 0; c < 4; c++) {
        ag[c] += __shfl_xor(ag[c], off);
        an[c] += __shfl_xor(an[c], off);
      }
    }
    if (lane == 0) {
      float H[4];
#pragma unroll
      for (int c = 0; c < 4; c++) {
        float v  = an[c] + bn[c];
        float sp = (v > 20.f) ? v : log1pf(expf(v));
        H[c] = (ag[c] + bg[c]) + noise[(size_t)row * NCOMP + c] * sp;
      }
      int k = 0; float best = H[0];
#pragma unroll
      for (int c = 1; c < 4; c++) { if (H[c] > best) { best = H[c]; k = c; } }
#pragma unroll
      for (int c = 0; c < 4; c++)
        Gout[(size_t)row * NCOMP + c] = (c <= k) ? 1.0f : 0.0f;
    }
  } else {
    const int tb  = bid - 1024;
    const int o_t = tb & 15, d_t = (tb >> 4) & 31, c = tb >> 9;
    const int d0 = d_t * 64, o0 = o_t * 64;
    const int col = tid & 63, rb = tid >> 6;

    const float* src = Wc + ((size_t)c * DDIM + d0) * DCOMP + o0;
#pragma unroll
    for (int i = 0; i < 16; i++) {
      int r = rb + i * 4;
      tile[r][col] = src[(size_t)r * DCOMP + col];
    }
    __syncthreads();
    short* dst = WcT + ((size_t)c * DCOMP + o0) * DDIM + d0;
    const int o   = tid >> 2;
    const int dsb = (tid & 3) * 16;
    bf16x8 p0, p1;
#pragma unroll
    for (int k = 0; k < 8; k++) {
      p0[k] = f2bf(tile[dsb + k][o]);
      p1[k] = f2bf(tile[dsb + 8 + k][o]);
    }
    *reinterpret_cast<bf16x8*>(dst + (size_t)o * DDIM + dsb)     = p0;
    *reinterpret_cast<bf16x8*>(dst + (size_t)o * DDIM + dsb + 8) = p1;
  }
}

// =======================================================================
// Main GEMM, round-12: r9 chassis (proven 72.3us: 16x16x32 MFMA, stage
// ledger, vmcnt(6)@p4/p8, 128KiB dbuf LDS, XOR swizzle, XCD 4x8 chunks)
// + ONE change: sched_barrier(0) between {ds_reads, stage} and s_barrier
// in each phase. Raw s_barrier is not a compiler scheduling fence, so
// without the pin hipcc may sink the ds_reads past the barrier, where the
// following lgkmcnt(0) exposes their full latency (suspected cause of the
// ~480cyc/phase gap, MfmaUtil 37% vs template's 62%). The pin keeps read
// ISSUE pre-barrier so they drain during barrier-wait. (Unlike r3's bad
// variant, nothing is pinned after the lgkm - next-phase reads still
// hoist into the MFMA cluster.)
// =======================================================================
constexpr int BM = 256, BN = 256, BK = 64;
constexpr int NT = DDIM / BK;    // 32 K-tiles
constexpr int HS = 128 * 64;     // shorts per half-tile (16 KB)

template<int MB, int NB>
__device__ __forceinline__ void MF(f32x4 (&acc)[8][4], bf16x8 (&a)[4][2], bf16x8 (&b)[2][2]) {
#pragma unroll
  for (int kh = 0; kh < 2; kh++)
#pragma unroll
    for (int ml = 0; ml < 4; ml++)
#pragma unroll
      for (int nl = 0; nl < 2; nl++)
        acc[MB + ml][NB + nl] = __builtin_amdgcn_mfma_f32_16x16x32_bf16(
            a[ml][kh], b[nl][kh], acc[MB + ml][NB + nl], 0, 0, 0);
}

// phase sync: PIN reads/stages pre-barrier -> barrier -> bare lgkm(0)
// (now ~free: reads drained during barrier wait) -> prio MFMA cluster.
#define PH_SYNC_MFMA(MB, NB, BREG)                           \
  __builtin_amdgcn_sched_barrier(0);                         \
  __builtin_amdgcn_s_barrier();                              \
  asm volatile("s_waitcnt lgkmcnt(0)");                      \
  __builtin_amdgcn_s_setprio(1);                             \
  MF<MB, NB>(acc, a, BREG);                                  \
  __builtin_amdgcn_s_setprio(0);

__global__ __launch_bounds__(512, 2) void gemm_kernel(
    const short* __restrict__ xb, const short* __restrict__ wt,
    const float* __restrict__ bc, const float* __restrict__ G,
    float* __restrict__ E) {
  __shared__ short Asm[2][2][HS];   // [buf][row-half][128r * 8slot * 8bf16]
  __shared__ short Bsm[2][2][HS];   // [buf][col-half][...]

  const int tid  = threadIdx.x;
  const int wave = tid >> 6, lane = tid & 63;
  const int wm = wave >> 2, wn = wave & 3;
  const int fr = lane & 15, fq = lane >> 4, l7 = lane & 7;

  // XCD swizzle: 16x16 tile grid, 8 XCDs, each owns a 4x8 chunk (col-major)
  const int xcd = blockIdx.x & 7, j = blockIdx.x >> 3;
  const int trow0 = (((xcd >> 1) << 2) + (j & 3)) * BM;
  const int tcol0 = (((xcd & 1) << 3) + (j >> 2)) * BN;

  const short* baseA[2] = { xb + (size_t)(trow0      ) * DDIM,
                            xb + (size_t)(trow0 + 128) * DDIM };
  const short* baseB[2] = { wt + (size_t)(tcol0      ) * DDIM,
                            wt + (size_t)(tcol0 + 128) * DDIM };

  // per-lane staging offsets (linear LDS dest, inverse-swizzled source)
  size_t soff[2]; int ldst[2];
#pragma unroll
  for (int l = 0; l < 2; l++) {
    int f = l * 512 + tid;
    int r = f >> 3;
    int s = (f & 7) ^ (r & 7);
    soff[l] = (size_t)r * DDIM + s * 8;
    ldst[l] = (l * 512 + wave * 64) * 8;   // wave-uniform LDS base (shorts)
  }

  auto STAGE = [&](const short* gb, int t, short* ldsh) {
#pragma unroll
    for (int l = 0; l < 2; l++)
      GLOAD_LDS16(gb + t * 64 + soff[l], ldsh + ldst[l]);
  };
  auto LDA = [&](const short* Ah, bf16x8 (&a)[4][2]) {
#pragma unroll
    for (int ml = 0; ml < 4; ml++) {
      int rh = wm * 64 + ml * 16 + fr;
#pragma unroll
      for (int kh = 0; kh < 2; kh++) {
        int sl = ((kh * 4 + fq) ^ l7) * 8;
        a[ml][kh] = *reinterpret_cast<const bf16x8*>(Ah + rh * 64 + sl);
      }
    }
  };
  auto LDB = [&](const short* Bh, bf16x8 (&b)[2][2]) {
#pragma unroll
    for (int nl = 0; nl < 2; nl++) {
      int ch = wn * 32 + nl * 16 + fr;
#pragma unroll
      for (int kh = 0; kh < 2; kh++) {
        int sl = ((kh * 4 + fq) ^ l7) * 8;
        b[nl][kh] = *reinterpret_cast<const bf16x8*>(Bh + ch * 64 + sl);
      }
    }
  };

  f32x4 acc[8][4];
#pragma unroll
  for (int m = 0; m < 8; m++)
#pragma unroll
    for (int n = 0; n < 4; n++) acc[m][n] = f32x4{0.f, 0.f, 0.f, 0.f};
  bf16x8 a[4][2], bA[2][2], bB[2][2];

  // ---- prologue: tile0 (4 halves) + tile1 {Ah0,Bh0,Bh1}; vmcnt(6) keeps
  // the tile1 trio in flight; tile1.Ah1 staged at p1 of iter 0. ----
  STAGE(baseA[0], 0, &Asm[0][0][0]);
  STAGE(baseB[0], 0, &Bsm[0][0][0]);
  STAGE(baseB[1], 0, &Bsm[0][1][0]);
  STAGE(baseA[1], 0, &Asm[0][1][0]);
  STAGE(baseA[0], 1, &Asm[1][0][0]);
  STAGE(baseB[0], 1, &Bsm[1][0][0]);
  STAGE(baseB[1], 1, &Bsm[1][1][0]);
  asm volatile("s_waitcnt vmcnt(6)" ::: "memory");
  __builtin_amdgcn_s_barrier();

  // ---- main loop (iters 0..NT/2-2, branch-free; r9 ledger verbatim) ----
  for (int i = 0; i < NT / 2 - 1; i++) {
    const int t1 = 2 * i + 1, t2 = 2 * i + 2, t3 = 2 * i + 3;

    // p1: (mh0, nh0) of buf0; bA <- B0.Bh0 (held through p4)
    LDA(&Asm[0][0][0], a); LDB(&Bsm[0][0][0], bA);
    STAGE(baseA[1], t1, &Asm[1][1][0]);
    PH_SYNC_MFMA(0, 0, bA);
    __builtin_amdgcn_s_barrier();
    // p2: (mh0, nh1); bB <- B0.Bh1
    LDB(&Bsm[0][1][0], bB);
    STAGE(baseA[0], t2, &Asm[0][0][0]);
    PH_SYNC_MFMA(0, 2, bB);
    __builtin_amdgcn_s_barrier();
    // p3: (mh1, nh1)
    LDA(&Asm[0][1][0], a);
    STAGE(baseB[0], t2, &Bsm[0][0][0]);
    PH_SYNC_MFMA(4, 2, bB);
    __builtin_amdgcn_s_barrier();
    // p4: (mh1, nh0) — pure registers + counted vmcnt
    STAGE(baseB[1], t2, &Bsm[0][1][0]);
    PH_SYNC_MFMA(4, 0, bA);
    asm volatile("s_waitcnt vmcnt(6)" ::: "memory");
    __builtin_amdgcn_s_barrier();
    // p5: (mh0, nh0) of buf1
    LDA(&Asm[1][0][0], a); LDB(&Bsm[1][0][0], bA);
    STAGE(baseA[1], t2, &Asm[0][1][0]);
    PH_SYNC_MFMA(0, 0, bA);
    __builtin_amdgcn_s_barrier();
    // p6: (mh0, nh1)
    LDB(&Bsm[1][1][0], bB);
    STAGE(baseA[0], t3, &Asm[1][0][0]);
    PH_SYNC_MFMA(0, 2, bB);
    __builtin_amdgcn_s_barrier();
    // p7: (mh1, nh1)
    LDA(&Asm[1][1][0], a);
    STAGE(baseB[0], t3, &Bsm[1][0][0]);
    PH_SYNC_MFMA(4, 2, bB);
    __builtin_amdgcn_s_barrier();
    // p8: (mh1, nh0) — pure registers + counted vmcnt
    STAGE(baseB[1], t3, &Bsm[1][1][0]);
    PH_SYNC_MFMA(4, 0, bA);
    asm volatile("s_waitcnt vmcnt(6)" ::: "memory");
    __builtin_amdgcn_s_barrier();
  }

  // ---- peeled last iteration (tiles NT-2 buf0, NT-1 buf1): keeps only
  // the p1 stage (buf1.Ah1 <- NT-1); p4's vmcnt(0) drains everything. ----
  {
    // p1
    LDA(&Asm[0][0][0], a); LDB(&Bsm[0][0][0], bA);
    STAGE(baseA[1], NT - 1, &Asm[1][1][0]);
    PH_SYNC_MFMA(0, 0, bA);
    __builtin_amdgcn_s_barrier();
    // p2
    LDB(&Bsm[0][1][0], bB);
    PH_SYNC_MFMA(0, 2, bB);
    __builtin_amdgcn_s_barrier();
    // p3
    LDA(&Asm[0][1][0], a);
    PH_SYNC_MFMA(4, 2, bB);
    __builtin_amdgcn_s_barrier();
    // p4 + full drain
    PH_SYNC_MFMA(4, 0, bA);
    asm volatile("s_waitcnt vmcnt(0)" ::: "memory");
    __builtin_amdgcn_s_barrier();
    // p5
    LDA(&Asm[1][0][0], a); LDB(&Bsm[1][0][0], bA);
    PH_SYNC_MFMA(0, 0, bA);
    __builtin_amdgcn_s_barrier();
    // p6
    LDB(&Bsm[1][1][0], bB);
    PH_SYNC_MFMA(0, 2, bB);
    __builtin_amdgcn_s_barrier();
    // p7
    LDA(&Asm[1][1][0], a);
    PH_SYNC_MFMA(4, 2, bB);
    __builtin_amdgcn_s_barrier();
    // p8
    PH_SYNC_MFMA(4, 0, bA);
  }

  // ---- epilogue: + bias, * mask, store f32 (r9 form, unchanged) ----
  const int comp = tcol0 >> 10;
  const float* __restrict__ bcn = bc + (size_t)comp * DCOMP + (tcol0 & (DCOMP - 1));
  float bias[4];
#pragma unroll
  for (int n = 0; n < 4; n++)
    bias[n] = bcn[((n >> 1) * 128) + wn * 32 + (n & 1) * 16 + fr];
#pragma unroll
  for (int m = 0; m < 8; m++) {
    int growb = trow0 + ((m >> 2) * 128) + wm * 64 + (m & 3) * 16 + fq * 4;
#pragma unroll
    for (int j2 = 0; j2 < 4; j2++) {
      int r = growb + j2;
      float mval = G[(size_t)r * NCOMP + comp];
      float* Erow = E + (size_t)r * NOUT + tcol0;
#pragma unroll
      for (int n = 0; n < 4; n++) {
        int coll = ((n >> 1) * 128) + wn * 32 + (n & 1) * 16 + fr;
        Erow[coll] = mval * (acc[m][n][j2] + bias[n]);
      }
    }
  }
}

extern "C" void kernel_launch(void* const* d_in, const int* in_sizes, int n_in,
                              void* d_out, int out_size, void* d_ws, size_t ws_size,
                              hipStream_t stream) {
  const float* x     = (const float*)d_in[0];
  const float* noise = (const float*)d_in[1];
  const float* Wc    = (const float*)d_in[2];
  const float* bc    = (const float*)d_in[3];
  const float* Wg    = (const float*)d_in[4];
  const float* bg    = (const float*)d_in[5];
  const float* Wn    = (const float*)d_in[6];
  const float* bn    = (const float*)d_in[7];

  float* E = (float*)d_out;                          // [4096, 4096]
  float* G = (float*)d_out + (size_t)BROWS * NOUT;   // [4096, 4]

  short* xb  = (short*)d_ws;                         // 16 MB bf16
  short* WcT = xb + (size_t)BROWS * DDIM;            // 16 MB bf16

  prep_kernel<<<3072, 256, 0, stream>>>(x, noise, Wg, bg, Wn, bn, Wc, G, xb, WcT);
  gemm_kernel<<<256, 512, 0, stream>>>(xb, WcT, bc, G, E);
}